// Round 2
// baseline (500.682 us; speedup 1.0000x reference)
//
#include <hip/hip_runtime.h>
#include <hip/hip_bf16.h>

typedef __bf16 bf16x8 __attribute__((ext_vector_type(8)));
typedef __bf16 bf16x2 __attribute__((ext_vector_type(2)));
typedef float  f32x4  __attribute__((ext_vector_type(4)));

#define MFMA16 __builtin_amdgcn_mfma_f32_16x16x32_bf16

__device__ __forceinline__ float fast_tanh(float x) {
    // tanh(x) = 1 - 2/(exp2(2*log2e*x)+1)
    float e = __builtin_amdgcn_exp2f(x * 2.8853900817779268f);
    return 1.0f - 2.0f * __builtin_amdgcn_rcpf(e + 1.0f);
}

// kappa permutation: stored k-index ke corresponds to physical k-dim
//   kphys = (ke & ~31) | ((ke&1)<<4) | ((ke>>1)&15)
// (inverse of kappa(32w+16nbl+c) = 32w+2c+nbl, used so GEMM epilogues can
//  write packed bf16x2 pairs; W2/W3 rows are permuted identically.)
__device__ __forceinline__ int kinv(int ke) {
    return (ke & ~31) | ((ke & 1) << 4) | ((ke >> 1) & 15);
}

__global__ __launch_bounds__(512, 2) void rel_kernel(
    const float* __restrict__ fwd, const float* __restrict__ bwd,
    const int* __restrict__ gold_heads, const int* __restrict__ gold_rels,
    const float* __restrict__ WFOH, const float* __restrict__ WFOM,
    const float* __restrict__ rcatBias, const float* __restrict__ rhid2Layer,
    const float* __restrict__ rhid2Bias, const float* __restrict__ routLayer,
    const float* __restrict__ routBias, float* __restrict__ out,
    int E, int NT)
{
    // LDS map (aliased; all 2D tiles XOR-swizzled with ((row&7)<<4) on bytes):
    //  [0,      65536): cat  128x256 bf16 (phys K)   | h2 128x128 bf16 (kappa2) [0,32768)
    //  [65536, 131072): h    128x256 bf16 (kappa K)  | sc 128x64  f32           [65536,98304)
    //  [98304, ...   ): fixup scratch (f32 exact path)
    __shared__ __align__(16) char smem[131072];
    __shared__ int sh_nfix;
    __shared__ int sh_fixlist[16];

    char* const sh_cat = smem;
    char* const sh_h   = smem + 65536;
    float* const fx_cat = (float*)(smem + 98304);   // 256
    float* const fx_h   = fx_cat + 256;             // 256
    float* const fx_h2  = fx_h + 256;               // 128
    float* const fx_p   = fx_h2 + 128;              // 512 partials

    const int tid   = threadIdx.x;
    const int w     = tid >> 6;
    const int lane  = tid & 63;
    const int row16 = lane & 15;
    const int g     = lane >> 4;
    const int xm    = (row16 & 7) << 4;
    const int q4    = w & 3;        // col-block for GEMM2/3
    const int hw    = w >> 2;       // row-half for GEMM2/3

    // ---------------- prologue: weights -> registers ----------------
    // GEMM1: wave w owns h-cols [32w,32w+32); W1 = [WFOH | WFOM] phys K
    bf16x8 w1f[2][8];
    #pragma unroll
    for (int nbl = 0; nbl < 2; ++nbl) {
        const int n = 32 * w + 16 * nbl + row16;
        const float* Wsrc = (32 * w + 16 * nbl < 128) ? WFOH : WFOM;  // wave-uniform
        const int col = n & 127;
        #pragma unroll
        for (int kk = 0; kk < 8; ++kk) {
            bf16x8 f;
            #pragma unroll
            for (int j = 0; j < 8; ++j) f[j] = (__bf16)Wsrc[(32 * kk + 8 * g + j) * 128 + col];
            w1f[nbl][kk] = f;
        }
    }
    // GEMM2: wave w owns h2-cols [32q4,32q4+32), rows [64hw,64hw+64); K kappa-permuted
    bf16x8 w2f[2][8];
    #pragma unroll
    for (int nbl = 0; nbl < 2; ++nbl) {
        const int n2 = 32 * q4 + 16 * nbl + row16;
        #pragma unroll
        for (int kk = 0; kk < 8; ++kk) {
            bf16x8 f;
            #pragma unroll
            for (int j = 0; j < 8; ++j) f[j] = (__bf16)rhid2Layer[kinv(32 * kk + 8 * g + j) * 128 + n2];
            w2f[nbl][kk] = f;
        }
    }
    // GEMM3: wave w owns label-cols [16q4,16q4+16), rows [64hw,64hw+64); K kappa2-permuted
    bf16x8 w3f[4];
    {
        const int n3 = 16 * q4 + row16;
        #pragma unroll
        for (int kk = 0; kk < 4; ++kk) {
            bf16x8 f;
            #pragma unroll
            for (int j = 0; j < 8; ++j) f[j] = (__bf16)routLayer[kinv(32 * kk + 8 * g + j) * 64 + n3];
            w3f[kk] = f;
        }
    }
    const float rcb0 = rcatBias[32 * w + row16];
    const float rcb1 = rcatBias[32 * w + 16 + row16];
    const float r2b0 = rhid2Bias[32 * q4 + row16];
    const float r2b1 = rhid2Bias[32 * q4 + 16 + row16];
    const float rob  = routBias[16 * q4 + row16];

    // staging map: thread -> (row, quarter of 64 floats)
    const int r_s = tid >> 2;
    const int q_s = tid & 3;
    const int xr  = (r_s & 7) << 4;

    float4 pf[16];
    auto load_tile = [&](int t) {
        const int e = t * 128 + r_s;
        if (e < E) {
            const float* src;
            if (q_s < 2) {
                const int head = gold_heads[e];
                src = fwd + (size_t)head * 128 + 64 * q_s;
            } else {
                src = bwd + (size_t)(e + 1) * 128 + 64 * (q_s - 2);
            }
            const float4* p4 = reinterpret_cast<const float4*>(src);
            #pragma unroll
            for (int i = 0; i < 16; ++i) pf[i] = p4[i];
        } else {
            #pragma unroll
            for (int i = 0; i < 16; ++i) pf[i] = make_float4(0.f, 0.f, 0.f, 0.f);
        }
    };

    load_tile(blockIdx.x);   // overlaps with weight prologue

    for (int tile = blockIdx.x; tile < NT; tile += gridDim.x) {
        const int e0 = tile * 128;

        // ---- stage cat (bf16, swizzled) from prefetch regs ----
        #pragma unroll
        for (int i = 0; i < 8; ++i) {
            bf16x8 v;
            v[0] = (__bf16)pf[2 * i].x;     v[1] = (__bf16)pf[2 * i].y;
            v[2] = (__bf16)pf[2 * i].z;     v[3] = (__bf16)pf[2 * i].w;
            v[4] = (__bf16)pf[2 * i + 1].x; v[5] = (__bf16)pf[2 * i + 1].y;
            v[6] = (__bf16)pf[2 * i + 1].z; v[7] = (__bf16)pf[2 * i + 1].w;
            *(bf16x8*)(sh_cat + r_s * 512 + ((128 * q_s + 16 * i) ^ xr)) = v;
        }
        __syncthreads();                                   // B1: cat ready

        // ---- GEMM1: h(128x256) = cat @ [WFOH|WFOM], tanh(+rcatBias) ----
        f32x4 acc1[8][2];
        #pragma unroll
        for (int mb = 0; mb < 8; ++mb) {
            acc1[mb][0] = (f32x4){0.f, 0.f, 0.f, 0.f};
            acc1[mb][1] = (f32x4){0.f, 0.f, 0.f, 0.f};
        }
        #pragma unroll
        for (int kk = 0; kk < 8; ++kk) {
            const int ko = (64 * kk + 16 * g) ^ xm;
            #pragma unroll
            for (int mb = 0; mb < 8; ++mb) {
                const bf16x8 a = *(const bf16x8*)(sh_cat + (16 * mb + row16) * 512 + ko);
                acc1[mb][0] = MFMA16(a, w1f[0][kk], acc1[mb][0], 0, 0, 0);
                acc1[mb][1] = MFMA16(a, w1f[1][kk], acc1[mb][1], 0, 0, 0);
            }
        }
        #pragma unroll
        for (int mb = 0; mb < 8; ++mb) {
            #pragma unroll
            for (int r = 0; r < 4; ++r) {
                const int row = 16 * mb + 4 * g + r;
                bf16x2 p;
                p[0] = (__bf16)fast_tanh(acc1[mb][0][r] + rcb0);
                p[1] = (__bf16)fast_tanh(acc1[mb][1][r] + rcb1);
                *(bf16x2*)(sh_h + row * 512 + ((64 * w + 4 * row16) ^ ((row & 7) << 4))) = p;
            }
        }
        __syncthreads();                                   // B2: h ready

        // ---- GEMM2: h2(128x128) = h @ W2(kappa), tanh(+rhid2Bias) ----
        f32x4 acc2[4][2];
        #pragma unroll
        for (int i = 0; i < 4; ++i) {
            acc2[i][0] = (f32x4){0.f, 0.f, 0.f, 0.f};
            acc2[i][1] = (f32x4){0.f, 0.f, 0.f, 0.f};
        }
        #pragma unroll
        for (int kk = 0; kk < 8; ++kk) {
            const int ko = (64 * kk + 16 * g) ^ xm;
            #pragma unroll
            for (int i = 0; i < 4; ++i) {
                const bf16x8 a = *(const bf16x8*)(sh_h + (16 * (4 * hw + i) + row16) * 512 + ko);
                acc2[i][0] = MFMA16(a, w2f[0][kk], acc2[i][0], 0, 0, 0);
                acc2[i][1] = MFMA16(a, w2f[1][kk], acc2[i][1], 0, 0, 0);
            }
        }
        // T14: issue next tile's gather now; consumed at next loop top
        if (tile + (int)gridDim.x < NT) load_tile(tile + gridDim.x);
        #pragma unroll
        for (int i = 0; i < 4; ++i) {
            #pragma unroll
            for (int r = 0; r < 4; ++r) {
                const int row = 16 * (4 * hw + i) + 4 * g + r;
                bf16x2 p;
                p[0] = (__bf16)fast_tanh(acc2[i][0][r] + r2b0);
                p[1] = (__bf16)fast_tanh(acc2[i][1][r] + r2b1);
                *(bf16x2*)(sh_cat + row * 256 + ((64 * q4 + 4 * row16) ^ ((row & 7) << 4))) = p;
            }
        }
        __syncthreads();                                   // B3: h2 ready

        // ---- GEMM3: sc(128x64) = h2 @ W3(kappa2) + routBias ----
        f32x4 acc3[4];
        #pragma unroll
        for (int i = 0; i < 4; ++i) acc3[i] = (f32x4){0.f, 0.f, 0.f, 0.f};
        if (tid == 0) sh_nfix = 0;
        #pragma unroll
        for (int kk = 0; kk < 4; ++kk) {
            const int ko = (64 * kk + 16 * g) ^ xm;
            #pragma unroll
            for (int i = 0; i < 4; ++i) {
                const bf16x8 a = *(const bf16x8*)(sh_cat + (16 * (4 * hw + i) + row16) * 256 + ko);
                acc3[i] = MFMA16(a, w3f[kk], acc3[i], 0, 0, 0);
            }
        }
        #pragma unroll
        for (int i = 0; i < 4; ++i) {
            #pragma unroll
            for (int r = 0; r < 4; ++r) {
                const int row = 16 * (4 * hw + i) + 4 * g + r;
                *(float*)(sh_h + row * 256 + ((64 * q4 + 4 * row16) ^ ((row & 7) << 4))) = acc3[i][r] + rob;
            }
        }
        __syncthreads();                                   // B4: sc ready

        // ---- hinge: 4 threads per edge row ----
        {
            const int r = tid >> 2, q = tid & 3;
            const int e = e0 + r;
            const int gold = (e < E) ? gold_rels[e] : 0;
            float gs = -3.0e38f, ws = -3.0e38f;
            #pragma unroll
            for (int c = 0; c < 4; ++c) {
                const f32x4 sv = *(const f32x4*)(sh_h + r * 256 + ((64 * q + 16 * c) ^ ((r & 7) << 4)));
                #pragma unroll
                for (int cc = 0; cc < 4; ++cc) {
                    const int lab = 16 * q + 4 * c + cc;
                    const float v = sv[cc];
                    if (lab == gold) gs = v; else ws = fmaxf(ws, v);
                }
            }
            gs = fmaxf(gs, __shfl_xor(gs, 1)); ws = fmaxf(ws, __shfl_xor(ws, 1));
            gs = fmaxf(gs, __shfl_xor(gs, 2)); ws = fmaxf(ws, __shfl_xor(ws, 2));
            if (q == 0 && e < E) {
                out[e] = (gs < ws + 1.0f) ? (ws - gs) : 0.0f;
                // hinge predicate is discontinuous at margin==1: flag for f32 fixup
                if (fabsf((gs - ws) - 1.0f) < 0.125f) {
                    const int idx = atomicAdd(&sh_nfix, 1);
                    if (idx < 16) sh_fixlist[idx] = r;
                }
            }
        }
        __syncthreads();                                   // B5: fixlist ready

        // ---- exact f32 recompute of margin-boundary edges (rare) ----
        int nf = sh_nfix; if (nf > 16) nf = 16;
        for (int fi = 0; fi < nf; ++fi) {
            const int e = e0 + sh_fixlist[fi];
            __syncthreads();
            if (tid < 256) {
                const int head = gold_heads[e];
                fx_cat[tid] = (tid < 128) ? fwd[(size_t)head * 128 + tid]
                                          : bwd[(size_t)(e + 1) * 128 + (tid - 128)];
            }
            __syncthreads();
            {   // layer1: 2 k-halves x 256 dims (coalesced weight reads)
                const int d = tid & 255, half = tid >> 8;
                const float* base = (d < 128) ? WFOH : WFOM;
                const int col = d & 127;
                float s = 0.f;
                #pragma unroll 8
                for (int k = 128 * half; k < 128 * half + 128; ++k) s += fx_cat[k] * base[k * 128 + col];
                fx_p[half * 256 + d] = s;
            }
            __syncthreads();
            if (tid < 256) fx_h[tid] = tanhf(fx_p[tid] + fx_p[256 + tid] + rcatBias[tid]);
            __syncthreads();
            {   // layer2: 4 k-quarters x 128 dims
                const int d2 = tid & 127, qq = tid >> 7;
                float s = 0.f;
                #pragma unroll 8
                for (int k = 64 * qq; k < 64 * qq + 64; ++k) s += fx_h[k] * rhid2Layer[k * 128 + d2];
                fx_p[qq * 128 + d2] = s;
            }
            __syncthreads();
            if (tid < 128) fx_h2[tid] = tanhf(fx_p[tid] + fx_p[128 + tid] + fx_p[256 + tid] + fx_p[384 + tid] + rhid2Bias[tid]);
            __syncthreads();
            if (tid < 64) {   // layer3 + hinge in one wave
                float s = 0.f;
                #pragma unroll 8
                for (int k = 0; k < 128; ++k) s += fx_h2[k] * routLayer[k * 64 + tid];
                const float v = s + routBias[tid];
                const int gold = gold_rels[e];
                float gs = (tid == gold) ? v : -3.0e38f;
                float ws = (tid == gold) ? -3.0e38f : v;
                #pragma unroll
                for (int o = 1; o < 64; o <<= 1) {
                    gs = fmaxf(gs, __shfl_xor(gs, o));
                    ws = fmaxf(ws, __shfl_xor(ws, o));
                }
                if (tid == 0) out[e] = (gs < ws + 1.0f) ? (ws - gs) : 0.0f;
            }
        }
    }
}

extern "C" void kernel_launch(void* const* d_in, const int* in_sizes, int n_in,
                              void* d_out, int out_size, void* d_ws, size_t ws_size,
                              hipStream_t stream) {
    const float* fwd        = (const float*)d_in[0];
    const float* bwd        = (const float*)d_in[1];
    const int*   gold_heads = (const int*)d_in[2];
    const int*   gold_rels  = (const int*)d_in[3];
    const float* WFOH       = (const float*)d_in[4];
    const float* WFOM       = (const float*)d_in[5];
    const float* rcatBias   = (const float*)d_in[7];   // d_in[6] rhidBias unused by reference
    const float* rhid2      = (const float*)d_in[8];
    const float* rhid2Bias  = (const float*)d_in[9];
    const float* rout       = (const float*)d_in[10];
    const float* routBias   = (const float*)d_in[11];
    float* out = (float*)d_out;

    const int E = in_sizes[2];
    if (E <= 0) return;
    const int NT = (E + 127) / 128;
    const int grid = NT < 256 ? NT : 256;

    hipLaunchKernelGGL(rel_kernel, dim3(grid), dim3(512), 0, stream,
                       fwd, bwd, gold_heads, gold_rels, WFOH, WFOM, rcatBias,
                       rhid2, rhid2Bias, rout, routBias, out, E, NT);
}

// Round 3
// 428.536 us; speedup vs baseline: 1.1684x; 1.1684x over previous
//
#include <hip/hip_runtime.h>
#include <hip/hip_bf16.h>

typedef __bf16 bf16x8 __attribute__((ext_vector_type(8)));
typedef __bf16 bf16x2 __attribute__((ext_vector_type(2)));
typedef float  f32x4  __attribute__((ext_vector_type(4)));

#define MFMA16 __builtin_amdgcn_mfma_f32_16x16x32_bf16

__device__ __forceinline__ float fast_tanh(float x) {
    // tanh(x) = 1 - 2/(exp2(2*log2e*x)+1)
    float e = __builtin_amdgcn_exp2f(x * 2.8853900817779268f);
    return 1.0f - 2.0f * __builtin_amdgcn_rcpf(e + 1.0f);
}

// kappa permutation: stored k-index ke -> physical k-dim
//   kphys = (ke & ~31) | ((ke&1)<<4) | ((ke>>1)&15)
// (inverse of kappa(32w+16nbl+c) = 32w+2c+nbl; lets GEMM epilogues write
//  packed bf16x2; W2/W3 rows permuted identically at prologue.)
__device__ __forceinline__ int kinv(int ke) {
    return (ke & ~31) | ((ke & 1) << 4) | ((ke >> 1) & 15);
}

__global__ __launch_bounds__(512) void rel_kernel(
    const float* __restrict__ fwd, const float* __restrict__ bwd,
    const int* __restrict__ gold_heads, const int* __restrict__ gold_rels,
    const float* __restrict__ WFOH, const float* __restrict__ WFOM,
    const float* __restrict__ rcatBias, const float* __restrict__ rhid2Layer,
    const float* __restrict__ rhid2Bias, const float* __restrict__ routLayer,
    const float* __restrict__ routBias, float* __restrict__ out,
    int E, int NT)
{
    // LDS map (aliased; 2D tiles XOR-swizzled with ((row&7)<<4) on bytes):
    //  [0,      65536): cat 128x256 bf16 (phys K) | h2 128x128 bf16 (kappa2) in [0,32768)
    //  [65536, 131072): h   128x256 bf16 (kappa)  | sc 128x64 f32 in [65536,98304)
    //                                             | fixup scratch in [98304,...)
    __shared__ __align__(16) char smem[131072];
    __shared__ int sh_nfix;
    __shared__ int sh_fixlist[16];

    char* const sh_cat = smem;
    char* const sh_h   = smem + 65536;
    float* const fx_cat = (float*)(smem + 98304);   // 256
    float* const fx_h   = fx_cat + 256;             // 256
    float* const fx_h2  = fx_h + 256;               // 128
    float* const fx_p   = fx_h2 + 128;              // 512 partials

    const int tid   = threadIdx.x;
    const int w     = tid >> 6;
    const int lane  = tid & 63;
    const int row16 = lane & 15;
    const int g     = lane >> 4;
    const int xm    = (row16 & 7) << 4;
    const int q4    = w & 3;        // col-block for GEMM2/3
    const int hw    = w >> 2;       // row-half for GEMM2/3

    // staging map: thread -> (row, quarter of 64 floats)
    const int r_s = tid >> 2;
    const int q_s = tid & 3;
    const int xr  = (r_s & 7) << 4;

    // ---- T14 gather pipeline: gh for next tile, then row loads, then cvt ----
    int nh = 0;
    auto load_gh = [&](int t) {
        const int e = t * 128 + r_s;
        if (e < E && q_s < 2) nh = gold_heads[e];
    };
    float4 pf[16];
    auto load_rows = [&](int t) {
        const int e = t * 128 + r_s;
        if (e < E) {
            const float* src = (q_s < 2) ? (fwd + (size_t)nh * 128 + 64 * q_s)
                                         : (bwd + (size_t)(e + 1) * 128 + 64 * (q_s - 2));
            const float4* p4 = reinterpret_cast<const float4*>(src);
            #pragma unroll
            for (int i = 0; i < 16; ++i) pf[i] = p4[i];
        } else {
            #pragma unroll
            for (int i = 0; i < 16; ++i) pf[i] = make_float4(0.f, 0.f, 0.f, 0.f);
        }
    };
    bf16x8 pfb[8];
    auto convert_pf = [&]() {
        #pragma unroll
        for (int i = 0; i < 8; ++i) {
            bf16x8 v;
            v[0] = (__bf16)pf[2 * i].x;     v[1] = (__bf16)pf[2 * i].y;
            v[2] = (__bf16)pf[2 * i].z;     v[3] = (__bf16)pf[2 * i].w;
            v[4] = (__bf16)pf[2 * i + 1].x; v[5] = (__bf16)pf[2 * i + 1].y;
            v[6] = (__bf16)pf[2 * i + 1].z; v[7] = (__bf16)pf[2 * i + 1].w;
            pfb[i] = v;
        }
    };

    load_gh(blockIdx.x);   // overlaps weight prologue

    // ---------------- prologue: weights -> registers ----------------
    // GEMM1: wave w owns h-cols [32w,32w+32); W1 = [WFOH | WFOM] phys K
    bf16x8 w1f[2][8];
    #pragma unroll
    for (int nbl = 0; nbl < 2; ++nbl) {
        const int n = 32 * w + 16 * nbl + row16;
        const float* Wsrc = (32 * w + 16 * nbl < 128) ? WFOH : WFOM;  // wave-uniform
        const int col = n & 127;
        #pragma unroll
        for (int kk = 0; kk < 8; ++kk) {
            bf16x8 f;
            #pragma unroll
            for (int j = 0; j < 8; ++j) f[j] = (__bf16)Wsrc[(32 * kk + 8 * g + j) * 128 + col];
            w1f[nbl][kk] = f;
        }
    }
    // GEMM2: wave w owns h2-cols [32q4,32q4+32), rows [64hw,64hw+64); K kappa
    bf16x8 w2f[2][8];
    #pragma unroll
    for (int nbl = 0; nbl < 2; ++nbl) {
        const int n2 = 32 * q4 + 16 * nbl + row16;
        #pragma unroll
        for (int kk = 0; kk < 8; ++kk) {
            bf16x8 f;
            #pragma unroll
            for (int j = 0; j < 8; ++j) f[j] = (__bf16)rhid2Layer[kinv(32 * kk + 8 * g + j) * 128 + n2];
            w2f[nbl][kk] = f;
        }
    }
    // GEMM3: wave w owns label-cols [16q4,16q4+16), rows [64hw,64hw+64); K kappa2
    bf16x8 w3f[4];
    {
        const int n3 = 16 * q4 + row16;
        #pragma unroll
        for (int kk = 0; kk < 4; ++kk) {
            bf16x8 f;
            #pragma unroll
            for (int j = 0; j < 8; ++j) f[j] = (__bf16)routLayer[kinv(32 * kk + 8 * g + j) * 64 + n3];
            w3f[kk] = f;
        }
    }
    const float rcb0 = rcatBias[32 * w + row16];
    const float rcb1 = rcatBias[32 * w + 16 + row16];
    const float r2b0 = rhid2Bias[32 * q4 + row16];
    const float r2b1 = rhid2Bias[32 * q4 + 16 + row16];
    const float rob  = routBias[16 * q4 + row16];

    load_rows(blockIdx.x);
    convert_pf();

    for (int tile = blockIdx.x; tile < NT; tile += gridDim.x) {
        const int e0 = tile * 128;

        // ---- stage cat (bf16, swizzled) from pfb ----
        #pragma unroll
        for (int i = 0; i < 8; ++i)
            *(bf16x8*)(sh_cat + r_s * 512 + ((128 * q_s + 16 * i) ^ xr)) = pfb[i];
        load_gh(tile + gridDim.x);          // next tile's head indices
        __syncthreads();                                   // B1: cat ready

        // ---- GEMM1: h(128x256) = cat @ [WFOH|WFOM], tanh(+rcatBias) ----
        // split into two mb-halves to halve accumulator pressure
        #pragma unroll
        for (int half = 0; half < 2; ++half) {
            f32x4 acc1[4][2];
            #pragma unroll
            for (int i = 0; i < 4; ++i) {
                acc1[i][0] = (f32x4){0.f, 0.f, 0.f, 0.f};
                acc1[i][1] = (f32x4){0.f, 0.f, 0.f, 0.f};
            }
            #pragma unroll
            for (int kk = 0; kk < 8; ++kk) {
                const int ko = (64 * kk + 16 * g) ^ xm;
                #pragma unroll
                for (int i = 0; i < 4; ++i) {
                    const int mb = 4 * half + i;
                    const bf16x8 a = *(const bf16x8*)(sh_cat + (16 * mb + row16) * 512 + ko);
                    acc1[i][0] = MFMA16(a, w1f[0][kk], acc1[i][0], 0, 0, 0);
                    acc1[i][1] = MFMA16(a, w1f[1][kk], acc1[i][1], 0, 0, 0);
                }
            }
            #pragma unroll
            for (int i = 0; i < 4; ++i) {
                #pragma unroll
                for (int r = 0; r < 4; ++r) {
                    const int row = 16 * (4 * half + i) + 4 * g + r;
                    bf16x2 p;
                    p[0] = (__bf16)fast_tanh(acc1[i][0][r] + rcb0);
                    p[1] = (__bf16)fast_tanh(acc1[i][1][r] + rcb1);
                    *(bf16x2*)(sh_h + row * 512 + ((64 * w + 4 * row16) ^ ((row & 7) << 4))) = p;
                }
            }
        }
        __syncthreads();                                   // B2: h ready

        // issue next tile's row gathers; consumed after GEMM3 (T14 split)
        if (tile + (int)gridDim.x < NT) load_rows(tile + gridDim.x);

        // ---- GEMM2: h2(128x128) = h @ W2(kappa), tanh(+rhid2Bias) ----
        f32x4 acc2[4][2];
        #pragma unroll
        for (int i = 0; i < 4; ++i) {
            acc2[i][0] = (f32x4){0.f, 0.f, 0.f, 0.f};
            acc2[i][1] = (f32x4){0.f, 0.f, 0.f, 0.f};
        }
        #pragma unroll
        for (int kk = 0; kk < 8; ++kk) {
            const int ko = (64 * kk + 16 * g) ^ xm;
            #pragma unroll
            for (int i = 0; i < 4; ++i) {
                const bf16x8 a = *(const bf16x8*)(sh_h + (16 * (4 * hw + i) + row16) * 512 + ko);
                acc2[i][0] = MFMA16(a, w2f[0][kk], acc2[i][0], 0, 0, 0);
                acc2[i][1] = MFMA16(a, w2f[1][kk], acc2[i][1], 0, 0, 0);
            }
        }
        #pragma unroll
        for (int i = 0; i < 4; ++i) {
            #pragma unroll
            for (int r = 0; r < 4; ++r) {
                const int row = 16 * (4 * hw + i) + 4 * g + r;
                bf16x2 p;
                p[0] = (__bf16)fast_tanh(acc2[i][0][r] + r2b0);
                p[1] = (__bf16)fast_tanh(acc2[i][1][r] + r2b1);
                *(bf16x2*)(sh_cat + row * 256 + ((64 * q4 + 4 * row16) ^ ((row & 7) << 4))) = p;
            }
        }
        __syncthreads();                                   // B3: h2 ready

        // ---- GEMM3: sc(128x64) = h2 @ W3(kappa2) + routBias ----
        f32x4 acc3[4];
        #pragma unroll
        for (int i = 0; i < 4; ++i) acc3[i] = (f32x4){0.f, 0.f, 0.f, 0.f};
        if (tid == 0) sh_nfix = 0;
        #pragma unroll
        for (int kk = 0; kk < 4; ++kk) {
            const int ko = (64 * kk + 16 * g) ^ xm;
            #pragma unroll
            for (int i = 0; i < 4; ++i) {
                const bf16x8 a = *(const bf16x8*)(sh_cat + (16 * (4 * hw + i) + row16) * 256 + ko);
                acc3[i] = MFMA16(a, w3f[kk], acc3[i], 0, 0, 0);
            }
        }
        #pragma unroll
        for (int i = 0; i < 4; ++i) {
            #pragma unroll
            for (int r = 0; r < 4; ++r) {
                const int row = 16 * (4 * hw + i) + 4 * g + r;
                *(float*)(sh_h + row * 256 + ((64 * q4 + 4 * row16) ^ ((row & 7) << 4))) = acc3[i][r] + rob;
            }
        }
        convert_pf();   // f32 gather regs -> bf16, frees 64 VGPRs for next phases
        __syncthreads();                                   // B4: sc ready

        // ---- hinge: 4 threads per edge row ----
        {
            const int r = tid >> 2, q = tid & 3;
            const int e = e0 + r;
            const int gold = (e < E) ? gold_rels[e] : 0;
            float gs = -3.0e38f, ws = -3.0e38f;
            #pragma unroll
            for (int c = 0; c < 4; ++c) {
                const f32x4 sv = *(const f32x4*)(sh_h + r * 256 + ((64 * q + 16 * c) ^ ((r & 7) << 4)));
                #pragma unroll
                for (int cc = 0; cc < 4; ++cc) {
                    const int lab = 16 * q + 4 * c + cc;
                    const float v = sv[cc];
                    if (lab == gold) gs = v; else ws = fmaxf(ws, v);
                }
            }
            gs = fmaxf(gs, __shfl_xor(gs, 1)); ws = fmaxf(ws, __shfl_xor(ws, 1));
            gs = fmaxf(gs, __shfl_xor(gs, 2)); ws = fmaxf(ws, __shfl_xor(ws, 2));
            if (q == 0 && e < E) {
                out[e] = (gs < ws + 1.0f) ? (ws - gs) : 0.0f;
                // hinge predicate is discontinuous at margin==1: flag for f32 fixup
                if (fabsf((gs - ws) - 1.0f) < 0.125f) {
                    const int idx = atomicAdd(&sh_nfix, 1);
                    if (idx < 16) sh_fixlist[idx] = r;
                }
            }
        }
        __syncthreads();                                   // B5: fixlist ready

        // ---- exact f32 recompute of margin-boundary edges (rare) ----
        int nf = sh_nfix; if (nf > 16) nf = 16;
        for (int fi = 0; fi < nf; ++fi) {
            const int e = e0 + sh_fixlist[fi];
            if (tid < 256) {
                const int head = gold_heads[e];
                fx_cat[tid] = (tid < 128) ? fwd[(size_t)head * 128 + tid]
                                          : bwd[(size_t)(e + 1) * 128 + (tid - 128)];
            }
            __syncthreads();
            {   // layer1: 2 k-halves x 256 dims (coalesced weight reads)
                const int d = tid & 255, half = tid >> 8;
                const float* base = (d < 128) ? WFOH : WFOM;
                const int col = d & 127;
                float s = 0.f;
                #pragma unroll 8
                for (int k = 128 * half; k < 128 * half + 128; ++k) s += fx_cat[k] * base[k * 128 + col];
                fx_p[half * 256 + d] = s;
            }
            __syncthreads();
            if (tid < 256) fx_h[tid] = tanhf(fx_p[tid] + fx_p[256 + tid] + rcatBias[tid]);
            __syncthreads();
            {   // layer2: 4 k-quarters x 128 dims
                const int d2 = tid & 127, qq = tid >> 7;
                float s = 0.f;
                #pragma unroll 8
                for (int k = 64 * qq; k < 64 * qq + 64; ++k) s += fx_h[k] * rhid2Layer[k * 128 + d2];
                fx_p[qq * 128 + d2] = s;
            }
            __syncthreads();
            if (tid < 128) fx_h2[tid] = tanhf(fx_p[tid] + fx_p[128 + tid] + fx_p[256 + tid] + fx_p[384 + tid] + rhid2Bias[tid]);
            __syncthreads();
            if (tid < 64) {   // layer3 + hinge in one wave
                float s = 0.f;
                #pragma unroll 8
                for (int k = 0; k < 128; ++k) s += fx_h2[k] * routLayer[k * 64 + tid];
                const float v = s + routBias[tid];
                const int gold = gold_rels[e];
                float gs = (tid == gold) ? v : -3.0e38f;
                float ws = (tid == gold) ? -3.0e38f : v;
                #pragma unroll
                for (int o = 1; o < 64; o <<= 1) {
                    gs = fmaxf(gs, __shfl_xor(gs, o));
                    ws = fmaxf(ws, __shfl_xor(ws, o));
                }
                if (tid == 0) out[e] = (gs < ws + 1.0f) ? (ws - gs) : 0.0f;
            }
            __syncthreads();
        }
    }
}

extern "C" void kernel_launch(void* const* d_in, const int* in_sizes, int n_in,
                              void* d_out, int out_size, void* d_ws, size_t ws_size,
                              hipStream_t stream) {
    const float* fwd        = (const float*)d_in[0];
    const float* bwd        = (const float*)d_in[1];
    const int*   gold_heads = (const int*)d_in[2];
    const int*   gold_rels  = (const int*)d_in[3];
    const float* WFOH       = (const float*)d_in[4];
    const float* WFOM       = (const float*)d_in[5];
    const float* rcatBias   = (const float*)d_in[7];   // d_in[6] rhidBias unused by reference
    const float* rhid2      = (const float*)d_in[8];
    const float* rhid2Bias  = (const float*)d_in[9];
    const float* rout       = (const float*)d_in[10];
    const float* routBias   = (const float*)d_in[11];
    float* out = (float*)d_out;

    const int E = in_sizes[2];
    if (E <= 0) return;
    const int NT = (E + 127) / 128;
    const int grid = NT < 256 ? NT : 256;

    hipLaunchKernelGGL(rel_kernel, dim3(grid), dim3(512), 0, stream,
                       fwd, bwd, gold_heads, gold_rels, WFOH, WFOM, rcatBias,
                       rhid2, rhid2Bias, rout, routBias, out, E, NT);
}

// Round 4
// 157.359 us; speedup vs baseline: 3.1818x; 2.7233x over previous
//
#include <hip/hip_runtime.h>
#include <hip/hip_bf16.h>

typedef __bf16 bf16x8 __attribute__((ext_vector_type(8)));
typedef __bf16 bf16x2 __attribute__((ext_vector_type(2)));
typedef float  f32x4  __attribute__((ext_vector_type(4)));

#define MFMA16 __builtin_amdgcn_mfma_f32_16x16x32_bf16

__device__ __forceinline__ float fast_tanh(float x) {
    // tanh(x) = 1 - 2/(exp2(2*log2e*x)+1)
    float e = __builtin_amdgcn_exp2f(x * 2.8853900817779268f);
    return 1.0f - 2.0f * __builtin_amdgcn_rcpf(e + 1.0f);
}

// kappa permutation: stored k-index ke -> physical k-dim
//   kphys = (ke & ~31) | ((ke&1)<<4) | ((ke>>1)&15)
// (lets GEMM1/GEMM2 epilogues write packed bf16x2; W2/W3 rows permuted to match)
__device__ __forceinline__ int kinv(int ke) {
    return (ke & ~31) | ((ke & 1) << 4) | ((ke >> 1) & 15);
}

// ---- weight pre-conversion: f32 -> bf16 MFMA B-fragments in d_ws ----
// table1 (GEMM1)  ws[0,      131072): [w:8][kk:8][nbl:2][lane:64][j:8 bf16]
// table2 (GEMM2)  ws[131072, 196608): [q4:4][kk:8][nbl:2][lane:64][j:8]
// table3 (GEMM3)  ws[196608, 212992): [q4:4][kk:4][lane:64][j:8]
__global__ __launch_bounds__(256) void preconv_kernel(
    const float* __restrict__ WFOH, const float* __restrict__ WFOM,
    const float* __restrict__ rhid2Layer, const float* __restrict__ routLayer,
    char* __restrict__ ws)
{
    const int f = blockIdx.x * 256 + threadIdx.x;
    bf16x8 v;
    char* dst;
    if (f < 8192) {
        const int lane = f & 63, t = f >> 6;
        const int nbl = t & 1, kk = (t >> 1) & 7, w = t >> 4;
        const int g = lane >> 4, c = lane & 15;
        const int nb = 32 * w + 16 * nbl;
        const float* Wsrc = (nb < 128) ? WFOH : WFOM;
        const int col = (nb + c) & 127;
        #pragma unroll
        for (int j = 0; j < 8; ++j) v[j] = (__bf16)Wsrc[(32 * kk + 8 * g + j) * 128 + col];
        dst = ws + (size_t)f * 16;
    } else if (f < 12288) {
        const int f2 = f - 8192;
        const int lane = f2 & 63, t = f2 >> 6;
        const int nbl = t & 1, kk = (t >> 1) & 7, q4 = t >> 4;
        const int g = lane >> 4, c = lane & 15;
        const int n2 = 32 * q4 + 16 * nbl + c;
        #pragma unroll
        for (int j = 0; j < 8; ++j) v[j] = (__bf16)rhid2Layer[kinv(32 * kk + 8 * g + j) * 128 + n2];
        dst = ws + 131072 + (size_t)f2 * 16;
    } else if (f < 13312) {
        const int f3 = f - 12288;
        const int lane = f3 & 63, t = f3 >> 6;
        const int kk = t & 3, q4 = t >> 2;
        const int g = lane >> 4, c = lane & 15;
        const int n3 = 16 * q4 + c;
        #pragma unroll
        for (int j = 0; j < 8; ++j) v[j] = (__bf16)routLayer[kinv(32 * kk + 8 * g + j) * 64 + n3];
        dst = ws + 196608 + (size_t)f3 * 16;
    } else {
        return;
    }
    *(bf16x8*)dst = v;
}

// ---- per-use weight fragment fetch (L2-resident either way) ----
template<bool PRE>
__device__ __forceinline__ bf16x8 wfrag1(const char* ws, const float* WFOH, const float* WFOM,
                                         int w, int kk, int nbl, int lane) {
    if constexpr (PRE) {
        return *(const bf16x8*)(ws + (size_t)w * 16384 + kk * 2048 + nbl * 1024 + lane * 16);
    } else {
        const int g = lane >> 4, c = lane & 15;
        const int nb = 32 * w + 16 * nbl;
        const float* Wsrc = (nb < 128) ? WFOH : WFOM;
        const int col = (nb + c) & 127;
        bf16x8 v;
        #pragma unroll
        for (int j = 0; j < 8; ++j) v[j] = (__bf16)Wsrc[(32 * kk + 8 * g + j) * 128 + col];
        return v;
    }
}
template<bool PRE>
__device__ __forceinline__ bf16x8 wfrag2(const char* ws, const float* rhid2Layer,
                                         int q4, int kk, int nbl, int lane) {
    if constexpr (PRE) {
        return *(const bf16x8*)(ws + 131072 + (size_t)q4 * 16384 + kk * 2048 + nbl * 1024 + lane * 16);
    } else {
        const int g = lane >> 4, c = lane & 15;
        const int n2 = 32 * q4 + 16 * nbl + c;
        bf16x8 v;
        #pragma unroll
        for (int j = 0; j < 8; ++j) v[j] = (__bf16)rhid2Layer[kinv(32 * kk + 8 * g + j) * 128 + n2];
        return v;
    }
}
template<bool PRE>
__device__ __forceinline__ bf16x8 wfrag3(const char* ws, const float* routLayer,
                                         int q4, int kk, int lane) {
    if constexpr (PRE) {
        return *(const bf16x8*)(ws + 196608 + (size_t)q4 * 4096 + kk * 1024 + lane * 16);
    } else {
        const int g = lane >> 4, c = lane & 15;
        const int n3 = 16 * q4 + c;
        bf16x8 v;
        #pragma unroll
        for (int j = 0; j < 8; ++j) v[j] = (__bf16)routLayer[kinv(32 * kk + 8 * g + j) * 64 + n3];
        return v;
    }
}

template<bool PRE>
__global__ __launch_bounds__(512, 2) void rel_kernel(
    const float* __restrict__ fwd, const float* __restrict__ bwd,
    const int* __restrict__ gold_heads, const int* __restrict__ gold_rels,
    const float* __restrict__ WFOH, const float* __restrict__ WFOM,
    const float* __restrict__ rcatBias, const float* __restrict__ rhid2Layer,
    const float* __restrict__ rhid2Bias, const float* __restrict__ routLayer,
    const float* __restrict__ routBias, const char* __restrict__ ws,
    float* __restrict__ out, int E, int NT)
{
    // LDS (aliased; 2D tiles XOR-swizzled with ((row&7)<<4) on bytes):
    //  [0,64K): cat 128x256 bf16 (phys K) | h2 128x128 bf16 (kappa2) in [0,32K)
    //  [64K,128K): h 128x256 bf16 (kappa) | sc 128x64 f32 in [64K,96K) | fixup in [96K,128K)
    __shared__ __align__(16) char smem[131072];
    __shared__ int sh_nfix;
    __shared__ int sh_fixlist[16];

    char* const sh_cat = smem;
    char* const sh_h   = smem + 65536;
    float* const fx_cat = (float*)(smem + 98304);   // 256
    float* const fx_h   = fx_cat + 256;             // 256
    float* const fx_h2  = fx_h + 256;               // 128
    float* const fx_p   = fx_h2 + 128;              // 512

    const int tid   = threadIdx.x;
    const int w     = tid >> 6;
    const int lane  = tid & 63;
    const int row16 = lane & 15;
    const int g     = lane >> 4;
    const int xm    = (row16 & 7) << 4;
    const int q4    = w & 3;
    const int hw    = w >> 2;

    const int r_s = tid >> 2;     // staging row
    const int q_s = tid & 3;      // staging quarter (64 floats each)
    const int xr  = (r_s & 7) << 4;

    const float rcb0 = rcatBias[32 * w + row16];
    const float rcb1 = rcatBias[32 * w + 16 + row16];
    const float r2b0 = rhid2Bias[32 * q4 + row16];
    const float r2b1 = rhid2Bias[32 * q4 + 16 + row16];
    const float rob  = routBias[16 * q4 + row16];

    // ---- prologue gather for the first tile ----
    bf16x8 pfb[8];
    {
        const int e = blockIdx.x * 128 + r_s;
        int nh = 0;
        if (q_s < 2 && e < E) nh = gold_heads[e];
        if (e < E) {
            const float* src = (q_s < 2) ? (fwd + (size_t)nh * 128 + 64 * q_s)
                                         : (bwd + (size_t)(e + 1) * 128 + 64 * (q_s - 2));
            const float4* p4 = (const float4*)src;
            #pragma unroll
            for (int i = 0; i < 8; ++i) {
                const float4 a = p4[2 * i], b = p4[2 * i + 1];
                bf16x8 t;
                t[0] = (__bf16)a.x; t[1] = (__bf16)a.y; t[2] = (__bf16)a.z; t[3] = (__bf16)a.w;
                t[4] = (__bf16)b.x; t[5] = (__bf16)b.y; t[6] = (__bf16)b.z; t[7] = (__bf16)b.w;
                pfb[i] = t;
            }
        } else {
            #pragma unroll
            for (int i = 0; i < 8; ++i) {
                bf16x8 t;
                #pragma unroll
                for (int j = 0; j < 8; ++j) t[j] = (__bf16)0.0f;
                pfb[i] = t;
            }
        }
    }

    for (int tile = blockIdx.x; tile < NT; tile += gridDim.x) {
        const int e0 = tile * 128;
        const int tnext = tile + gridDim.x;
        const bool hn = tnext < NT;

        // ---- stage cat tile (bf16, swizzled) from pfb ----
        #pragma unroll
        for (int i = 0; i < 8; ++i)
            *(bf16x8*)(sh_cat + r_s * 512 + ((128 * q_s + 16 * i) ^ xr)) = pfb[i];

        // next tile's head index (latency hidden under GEMM1)
        int nh = 0;
        bool gv = false;
        if (hn) {
            const int en = tnext * 128 + r_s;
            gv = en < E;
            if (q_s < 2 && gv) nh = gold_heads[en];
        }
        __syncthreads();                                   // B1: cat ready

        // ---- GEMM1: h(128x256) = cat @ [WFOH|WFOM], tanh(+rcatBias) ----
        f32x4 acc1[8][2];
        #pragma unroll
        for (int i = 0; i < 8; ++i) {
            acc1[i][0] = (f32x4){0.f, 0.f, 0.f, 0.f};
            acc1[i][1] = (f32x4){0.f, 0.f, 0.f, 0.f};
        }
        #pragma unroll 1   // rolled: bounds in-flight weight-frag registers
        for (int kk = 0; kk < 8; ++kk) {
            const bf16x8 b0 = wfrag1<PRE>(ws, WFOH, WFOM, w, kk, 0, lane);
            const bf16x8 b1 = wfrag1<PRE>(ws, WFOH, WFOM, w, kk, 1, lane);
            const int ko = (64 * kk + 16 * g) ^ xm;
            #pragma unroll
            for (int mb = 0; mb < 8; ++mb) {
                const bf16x8 a = *(const bf16x8*)(sh_cat + (16 * mb + row16) * 512 + ko);
                acc1[mb][0] = MFMA16(a, b0, acc1[mb][0], 0, 0, 0);
                acc1[mb][1] = MFMA16(a, b1, acc1[mb][1], 0, 0, 0);
            }
        }
        #pragma unroll
        for (int mb = 0; mb < 8; ++mb) {
            #pragma unroll
            for (int r = 0; r < 4; ++r) {
                const int row = 16 * mb + 4 * g + r;
                bf16x2 p;
                p[0] = (__bf16)fast_tanh(acc1[mb][0][r] + rcb0);
                p[1] = (__bf16)fast_tanh(acc1[mb][1][r] + rcb1);
                *(bf16x2*)(sh_h + row * 512 + ((64 * w + 4 * row16) ^ ((row & 7) << 4))) = p;
            }
        }
        __syncthreads();                                   // B2: h ready

        // ---- gather batch A for next tile (T14: issue early, convert late) ----
        const float* gsrc = nullptr;
        if (hn) {
            const int en = tnext * 128 + r_s;
            gsrc = (q_s < 2) ? (fwd + (size_t)nh * 128 + 64 * q_s)
                             : (bwd + (size_t)(en + 1) * 128 + 64 * (q_s - 2));
        }
        float4 pfA[8];
        if (hn && gv) {
            const float4* p4 = (const float4*)gsrc;
            #pragma unroll
            for (int i = 0; i < 8; ++i) pfA[i] = p4[i];
        } else {
            #pragma unroll
            for (int i = 0; i < 8; ++i) pfA[i] = make_float4(0.f, 0.f, 0.f, 0.f);
        }

        // ---- GEMM2: h2(128x128) = h @ W2(kappa), tanh(+rhid2Bias) ----
        f32x4 acc2[4][2];
        #pragma unroll
        for (int i = 0; i < 4; ++i) {
            acc2[i][0] = (f32x4){0.f, 0.f, 0.f, 0.f};
            acc2[i][1] = (f32x4){0.f, 0.f, 0.f, 0.f};
        }
        #pragma unroll 1
        for (int kk = 0; kk < 8; ++kk) {
            const bf16x8 b0 = wfrag2<PRE>(ws, rhid2Layer, q4, kk, 0, lane);
            const bf16x8 b1 = wfrag2<PRE>(ws, rhid2Layer, q4, kk, 1, lane);
            const int ko = (64 * kk + 16 * g) ^ xm;
            #pragma unroll
            for (int i = 0; i < 4; ++i) {
                const bf16x8 a = *(const bf16x8*)(sh_h + (16 * (4 * hw + i) + row16) * 512 + ko);
                acc2[i][0] = MFMA16(a, b0, acc2[i][0], 0, 0, 0);
                acc2[i][1] = MFMA16(a, b1, acc2[i][1], 0, 0, 0);
            }
        }
        // convert batch A -> pfb[0..3]; then issue batch B
        #pragma unroll
        for (int i = 0; i < 4; ++i) {
            const float4 a = pfA[2 * i], b = pfA[2 * i + 1];
            bf16x8 t;
            t[0] = (__bf16)a.x; t[1] = (__bf16)a.y; t[2] = (__bf16)a.z; t[3] = (__bf16)a.w;
            t[4] = (__bf16)b.x; t[5] = (__bf16)b.y; t[6] = (__bf16)b.z; t[7] = (__bf16)b.w;
            pfb[i] = t;
        }
        float4 pfB[8];
        if (hn && gv) {
            const float4* p4 = (const float4*)gsrc;
            #pragma unroll
            for (int i = 0; i < 8; ++i) pfB[i] = p4[8 + i];
        } else {
            #pragma unroll
            for (int i = 0; i < 8; ++i) pfB[i] = make_float4(0.f, 0.f, 0.f, 0.f);
        }
        #pragma unroll
        for (int i = 0; i < 4; ++i) {
            #pragma unroll
            for (int r = 0; r < 4; ++r) {
                const int row = 16 * (4 * hw + i) + 4 * g + r;
                bf16x2 p;
                p[0] = (__bf16)fast_tanh(acc2[i][0][r] + r2b0);
                p[1] = (__bf16)fast_tanh(acc2[i][1][r] + r2b1);
                *(bf16x2*)(sh_cat + row * 256 + ((64 * q4 + 4 * row16) ^ ((row & 7) << 4))) = p;
            }
        }
        __syncthreads();                                   // B3: h2 ready

        // ---- GEMM3: sc(128x64) = h2 @ W3(kappa2) + routBias ----
        if (tid == 0) sh_nfix = 0;
        f32x4 acc3[4];
        #pragma unroll
        for (int i = 0; i < 4; ++i) acc3[i] = (f32x4){0.f, 0.f, 0.f, 0.f};
        #pragma unroll
        for (int kk = 0; kk < 4; ++kk) {
            const bf16x8 b = wfrag3<PRE>(ws, routLayer, q4, kk, lane);
            const int ko = (64 * kk + 16 * g) ^ xm;
            #pragma unroll
            for (int i = 0; i < 4; ++i) {
                const bf16x8 a = *(const bf16x8*)(sh_cat + (16 * (4 * hw + i) + row16) * 256 + ko);
                acc3[i] = MFMA16(a, b, acc3[i], 0, 0, 0);
            }
        }
        // convert batch B -> pfb[4..7]
        #pragma unroll
        for (int i = 0; i < 4; ++i) {
            const float4 a = pfB[2 * i], b = pfB[2 * i + 1];
            bf16x8 t;
            t[0] = (__bf16)a.x; t[1] = (__bf16)a.y; t[2] = (__bf16)a.z; t[3] = (__bf16)a.w;
            t[4] = (__bf16)b.x; t[5] = (__bf16)b.y; t[6] = (__bf16)b.z; t[7] = (__bf16)b.w;
            pfb[4 + i] = t;
        }
        #pragma unroll
        for (int i = 0; i < 4; ++i) {
            #pragma unroll
            for (int r = 0; r < 4; ++r) {
                const int row = 16 * (4 * hw + i) + 4 * g + r;
                *(float*)(sh_h + row * 256 + ((64 * q4 + 4 * row16) ^ ((row & 7) << 4))) = acc3[i][r] + rob;
            }
        }
        __syncthreads();                                   // B4: sc ready

        // ---- hinge: 4 threads per edge row ----
        {
            const int r = tid >> 2, q = tid & 3;
            const int e = e0 + r;
            const int gold = (e < E) ? gold_rels[e] : 0;
            float gs = -3.0e38f, ws_ = -3.0e38f;
            #pragma unroll
            for (int c = 0; c < 4; ++c) {
                const f32x4 sv = *(const f32x4*)(sh_h + r * 256 + ((64 * q + 16 * c) ^ ((r & 7) << 4)));
                #pragma unroll
                for (int cc = 0; cc < 4; ++cc) {
                    const int lab = 16 * q + 4 * c + cc;
                    const float v = sv[cc];
                    if (lab == gold) gs = v; else ws_ = fmaxf(ws_, v);
                }
            }
            gs = fmaxf(gs, __shfl_xor(gs, 1)); ws_ = fmaxf(ws_, __shfl_xor(ws_, 1));
            gs = fmaxf(gs, __shfl_xor(gs, 2)); ws_ = fmaxf(ws_, __shfl_xor(ws_, 2));
            if (q == 0 && e < E) {
                out[e] = (gs < ws_ + 1.0f) ? (ws_ - gs) : 0.0f;
                // hinge predicate discontinuous at margin==1 -> exact f32 fixup
                if (fabsf((gs - ws_) - 1.0f) < 0.125f) {
                    const int idx = atomicAdd(&sh_nfix, 1);
                    if (idx < 16) sh_fixlist[idx] = r;
                }
            }
        }
        __syncthreads();                                   // B5: fixlist ready

        // ---- exact f32 recompute of margin-boundary edges (rare) ----
        int nf = sh_nfix; if (nf > 16) nf = 16;
        for (int fi = 0; fi < nf; ++fi) {
            const int e = e0 + sh_fixlist[fi];
            if (tid < 256) {
                const int head = gold_heads[e];
                fx_cat[tid] = (tid < 128) ? fwd[(size_t)head * 128 + tid]
                                          : bwd[(size_t)(e + 1) * 128 + (tid - 128)];
            }
            __syncthreads();
            {   // layer1: 2 k-halves x 256 dims (coalesced weight reads)
                const int d = tid & 255, half = tid >> 8;
                const float* base = (d < 128) ? WFOH : WFOM;
                const int col = d & 127;
                float s = 0.f;
                #pragma unroll 8
                for (int k = 128 * half; k < 128 * half + 128; ++k) s += fx_cat[k] * base[k * 128 + col];
                fx_p[half * 256 + d] = s;
            }
            __syncthreads();
            if (tid < 256) fx_h[tid] = tanhf(fx_p[tid] + fx_p[256 + tid] + rcatBias[tid]);
            __syncthreads();
            {   // layer2: 4 k-quarters x 128 dims
                const int d2 = tid & 127, qq = tid >> 7;
                float s = 0.f;
                #pragma unroll 8
                for (int k = 64 * qq; k < 64 * qq + 64; ++k) s += fx_h[k] * rhid2Layer[k * 128 + d2];
                fx_p[qq * 128 + d2] = s;
            }
            __syncthreads();
            if (tid < 128) fx_h2[tid] = tanhf(fx_p[tid] + fx_p[128 + tid] + fx_p[256 + tid] + fx_p[384 + tid] + rhid2Bias[tid]);
            __syncthreads();
            if (tid < 64) {   // layer3 + hinge in one wave
                float s = 0.f;
                #pragma unroll 8
                for (int k = 0; k < 128; ++k) s += fx_h2[k] * routLayer[k * 64 + tid];
                const float v = s + routBias[tid];
                const int gold = gold_rels[e];
                float gs = (tid == gold) ? v : -3.0e38f;
                float wv = (tid == gold) ? -3.0e38f : v;
                #pragma unroll
                for (int o = 1; o < 64; o <<= 1) {
                    gs = fmaxf(gs, __shfl_xor(gs, o));
                    wv = fmaxf(wv, __shfl_xor(wv, o));
                }
                if (tid == 0) out[e] = (gs < wv + 1.0f) ? (wv - gs) : 0.0f;
            }
            __syncthreads();
        }
    }
}

extern "C" void kernel_launch(void* const* d_in, const int* in_sizes, int n_in,
                              void* d_out, int out_size, void* d_ws, size_t ws_size,
                              hipStream_t stream) {
    const float* fwd        = (const float*)d_in[0];
    const float* bwd        = (const float*)d_in[1];
    const int*   gold_heads = (const int*)d_in[2];
    const int*   gold_rels  = (const int*)d_in[3];
    const float* WFOH       = (const float*)d_in[4];
    const float* WFOM       = (const float*)d_in[5];
    const float* rcatBias   = (const float*)d_in[7];   // d_in[6] rhidBias unused by reference
    const float* rhid2      = (const float*)d_in[8];
    const float* rhid2Bias  = (const float*)d_in[9];
    const float* rout       = (const float*)d_in[10];
    const float* routBias   = (const float*)d_in[11];
    float* out = (float*)d_out;

    const int E = in_sizes[2];
    if (E <= 0) return;
    const int NT = (E + 127) / 128;
    const int grid = NT < 256 ? NT : 256;

    if (ws_size >= (size_t)212992) {
        hipLaunchKernelGGL(preconv_kernel, dim3(52), dim3(256), 0, stream,
                           WFOH, WFOM, rhid2, rout, (char*)d_ws);
        hipLaunchKernelGGL((rel_kernel<true>), dim3(grid), dim3(512), 0, stream,
                           fwd, bwd, gold_heads, gold_rels, WFOH, WFOM, rcatBias,
                           rhid2, rhid2Bias, rout, routBias, (const char*)d_ws, out, E, NT);
    } else {
        hipLaunchKernelGGL((rel_kernel<false>), dim3(grid), dim3(512), 0, stream,
                           fwd, bwd, gold_heads, gold_rels, WFOH, WFOM, rcatBias,
                           rhid2, rhid2Bias, rout, routBias, (const char*)nullptr, out, E, NT);
    }
}